// Round 3
// baseline (170.568 us; speedup 1.0000x reference)
//
#include <hip/hip_runtime.h>

#define TPG   4096    // nodes per graph (T)
#define NHEAD 4
#define DIMD  128
#define NEG   0.2f

// ---------------------------------------------------------------- edge loads
__device__ __forceinline__ int load_edge(const void* ei, int is64, long idx) {
  if (is64) return (int)((const long long*)ei)[idx];
  return ((const int*)ei)[idx];
}

// Per-block int64/int32 layout vote: 256 threads sample odd dwords 1..511.
// int64 => high dwords all 0. int32 => those dwords are node ids ~U[0,4096),
// 256 simultaneous zeros is impossible in practice.
__device__ __forceinline__ int detect64_block(const unsigned* __restrict__ ei) {
  __shared__ int s64;
  int t = threadIdx.x;
  if (t == 0) s64 = 1;
  __syncthreads();
  if (t < 256) {
    unsigned v = ei[2 * t + 1];
    if (v != 0u) s64 = 0;     // benign race: all writers write 0
  }
  __syncthreads();
  return s64;
}

// ------------------------------------------------- GEMM h = x*W^T + att dots
// block = 256 threads, 16 nodes/block. thread(n_sub = t&15, cgrp = t>>4)
// computes 8 channels. Wave w owns head w. Blocks 0..15 also zero the hist
// counters; block 16 zeroes the done counter (k_histscan runs after us).
__global__ __launch_bounds__(256) void k_gemm(
    const float* __restrict__ x, const float* __restrict__ W,
    const float* __restrict__ atts, const float* __restrict__ attd,
    float* __restrict__ h, float* __restrict__ as_n, float* __restrict__ ad_n,
    int* __restrict__ counts, int* __restrict__ done) {
  __shared__ float4 xs4[16][33];   // +1 float4 pad
  int t = threadIdx.x;
  if (blockIdx.x < 16) counts[(blockIdx.x << 8) + t] = 0;
  if (blockIdx.x == 16 && t == 0) *done = 0;
  int base = blockIdx.x * 16;
  const float4* x4 = (const float4*)x;
  for (int i = t; i < 512; i += 256) {
    xs4[i >> 5][i & 31] = x4[base * 32 + i];
  }
  __syncthreads();

  int n_sub = t & 15, cgrp = t >> 4;
  int c0 = cgrp * 8;
  const float4* W4 = (const float4*)W;
  float acc[8];
#pragma unroll
  for (int k = 0; k < 8; ++k) acc[k] = 0.f;

  for (int db = 0; db < 32; db += 8) {     // 32 d per chunk
    float4 xa[8];
#pragma unroll
    for (int i = 0; i < 8; ++i) xa[i] = xs4[n_sub][db + i];
#pragma unroll
    for (int k = 0; k < 8; ++k) {
      const float4* wr = W4 + (c0 + k) * 32 + db;
      float a = acc[k];
#pragma unroll
      for (int i = 0; i < 8; ++i) {
        float4 w = wr[i];
        a = fmaf(xa[i].x, w.x, a);
        a = fmaf(xa[i].y, w.y, a);
        a = fmaf(xa[i].z, w.z, a);
        a = fmaf(xa[i].w, w.w, a);
      }
      acc[k] = a;
    }
  }

  int n = base + n_sub;
  float4* hp = (float4*)(h + ((size_t)n << 7) + c0);
  hp[0] = make_float4(acc[0], acc[1], acc[2], acc[3]);
  hp[1] = make_float4(acc[4], acc[5], acc[6], acc[7]);

  float ps = 0.f, pd = 0.f;
#pragma unroll
  for (int k = 0; k < 8; ++k) {
    ps = fmaf(acc[k], atts[c0 + k], ps);
    pd = fmaf(acc[k], attd[c0 + k], pd);
  }
  ps += __shfl_xor(ps, 16); ps += __shfl_xor(ps, 32);
  pd += __shfl_xor(pd, 16); pd += __shfl_xor(pd, 32);
  if ((t & 48) == 0) {
    as_n[(n << 2) + (t >> 6)] = ps;
    ad_n[(n << 2) + (t >> 6)] = pd;
  }
}

// --------------------------------------- CSR: histogram + last-block scan
__global__ __launch_bounds__(256) void k_histscan(
    const void* __restrict__ ei, int* __restrict__ counts,
    int* __restrict__ offs, int* __restrict__ cursor,
    int* __restrict__ done, int E) {
  int is64 = detect64_block((const unsigned*)ei);
  int t = threadIdx.x;
  int e = blockIdx.x * 256 + t;
  if (e < E) {
    int dst = load_edge(ei, is64, (long)E + e);
    atomicAdd(&counts[dst], 1);
  }
  __syncthreads();                       // barrier drains vmcnt: atomics acked
  __shared__ int lastFlag;
  if (t == 0) {
    __threadfence();
    int prev = atomicAdd(done, 1);
    lastFlag = (prev == (int)gridDim.x - 1);
  }
  __syncthreads();
  if (!lastFlag) return;

  // last arriving block: scan the 4096 counters (coherent atomic reads)
  int v[16]; int sum = 0;
#pragma unroll
  for (int i = 0; i < 16; ++i) { v[i] = atomicAdd(&counts[t * 16 + i], 0); sum += v[i]; }
  int lane = t & 63, w = t >> 6;
  int sc = sum;
#pragma unroll
  for (int off = 1; off < 64; off <<= 1) {
    int o = __shfl_up(sc, off);
    if (lane >= off) sc += o;
  }
  __shared__ int wsum[4];
  if (lane == 63) wsum[w] = sc;
  __syncthreads();
  int wo = 0;
  for (int i = 0; i < w; ++i) wo += wsum[i];
  int a = wo + sc - sum;
#pragma unroll
  for (int i = 0; i < 16; ++i) {
    offs[t * 16 + i] = a; cursor[t * 16 + i] = a; a += v[i];
  }
  if (t == 255) offs[4096] = a;
}

__global__ __launch_bounds__(256) void k_scatter(const void* __restrict__ ei,
                                                 int* __restrict__ cursor,
                                                 int* __restrict__ esrc, int E) {
  int is64 = detect64_block((const unsigned*)ei);
  int e = blockIdx.x * blockDim.x + threadIdx.x;
  if (e >= E) return;
  int src = load_edge(ei, is64, e);
  int dst = load_edge(ei, is64, (long)E + e);
  int pos = atomicAdd(&cursor[dst], 1);
  esrc[pos] = src;
}

// --------------------------- single-pass flash softmax + aggregation per node
// 2 waves per node (head-split): wave handles heads {0,1} or {2,3}; each lane
// owns ONE channel. XCD-aware swizzle pins graph g to XCDs {2g,2g+1} so its
// 2MB h-slice is L2-resident. Edges in batches of 8: wave-uniform scalar esrc
// loads, 8 h gathers in flight, branch-free rescale. No shfl, no atomics.
__global__ __launch_bounds__(256) void k_aggr(
    const int* __restrict__ offs, const int* __restrict__ esrc,
    const float* __restrict__ h, const float* __restrict__ as_n,
    const float* __restrict__ ad_n, const float* __restrict__ bias,
    float* __restrict__ out) {
  int bid = blockIdx.x;                  // 8192 blocks, 2 nodes/block
  int wv = threadIdx.x >> 6;             // 0..3
  int lane = threadIdx.x & 63;
  int xcd = bid & 7, slot = bid >> 3;    // assumes round-robin block->XCD
  int g = xcd >> 1, pair = xcd & 1;
  int group = (slot << 1) + pair;        // 0..2047 within graph
  int n = (g << 12) + (group << 1) + (wv >> 1);
  n = __builtin_amdgcn_readfirstlane(n);
  int hpair = wv & 1;
  int tloc = n & (TPG - 1);
  int nodebase = n - tloc;
  int beg = __builtin_amdgcn_readfirstlane(offs[tloc]);
  int end = __builtin_amdgcn_readfirstlane(offs[tloc + 1]);

  int hh = (hpair << 1) + (lane >> 5);   // head 0..3
  int ch = (hh << 5) + (lane & 31);      // channel 0..127
  float adst = ad_n[(n << 2) + hh];

  float m, s, acc;
  {
    float e = as_n[(n << 2) + hh] + adst;    // self-loop
    e = e > 0.f ? e : NEG * e;
    m = e; s = 1.f;
    acc = h[((size_t)n << 7) + ch];
  }

  for (int j0 = beg; j0 < end; j0 += 8) {
    int sgk[8];
#pragma unroll
    for (int k = 0; k < 8; ++k) {
      int j = j0 + k;
      sgk[k] = (j < end) ? (nodebase + esrc[j]) : n;   // uniform -> s_load
    }
    float hv[8];
#pragma unroll
    for (int k = 0; k < 8; ++k) hv[k] = h[((size_t)sgk[k] << 7) + ch];
    float ek[8];
#pragma unroll
    for (int k = 0; k < 8; ++k) {
      float e = as_n[(sgk[k] << 2) + hh] + adst;
      e = e > 0.f ? e : NEG * e;
      ek[k] = (j0 + k < end) ? e : -1e30f;             // tail contributes 0
    }
    float bm = fmaxf(fmaxf(fmaxf(ek[0], ek[1]), fmaxf(ek[2], ek[3])),
                     fmaxf(fmaxf(ek[4], ek[5]), fmaxf(ek[6], ek[7])));
    float mn = fmaxf(m, bm);
    float r = __expf(m - mn);
    float ps = 0.f, pa = 0.f;
#pragma unroll
    for (int k = 0; k < 8; ++k) {
      float al = __expf(ek[k] - mn);
      ps += al;
      pa = fmaf(al, hv[k], pa);
    }
    acc = fmaf(acc, r, pa);
    s = fmaf(s, r, ps);
    m = mn;
  }

  float invs = 1.f / (s + 1e-16f);
  out[((size_t)n << 7) + ch] = fmaf(acc, invs, bias[ch]);
}

// ---------------------------------------------------------------------- host
extern "C" void kernel_launch(void* const* d_in, const int* in_sizes, int n_in,
                              void* d_out, int out_size, void* d_ws, size_t ws_size,
                              hipStream_t stream) {
  const float* x    = (const float*)d_in[0];
  const void*  ei   = d_in[1];
  const float* W    = (const float*)d_in[2];
  const float* atts = (const float*)d_in[3];
  const float* attd = (const float*)d_in[4];
  const float* bias = (const float*)d_in[5];
  float* out = (float*)d_out;

  int N = in_sizes[0] / DIMD;   // 16384
  int E = in_sizes[1] / 2;      // 131072

  char* p = (char*)d_ws;
  float* h      = (float*)p; p += (size_t)N * DIMD * 4;
  float* as_n   = (float*)p; p += (size_t)N * NHEAD * 4;
  float* ad_n   = (float*)p; p += (size_t)N * NHEAD * 4;
  int*   counts = (int*)p;   p += (size_t)TPG * 4;
  int*   offs   = (int*)p;   p += (size_t)(TPG + 1) * 4;
  int*   cursor = (int*)p;   p += (size_t)TPG * 4;
  int*   esrc   = (int*)p;   p += (size_t)E * 4;
  int*   done   = (int*)p;   p += 4;

  k_gemm<<<N / 16, 256, 0, stream>>>(x, W, atts, attd, h, as_n, ad_n, counts, done);
  k_histscan<<<(E + 255) / 256, 256, 0, stream>>>(ei, counts, offs, cursor, done, E);
  k_scatter<<<(E + 255) / 256, 256, 0, stream>>>(ei, cursor, esrc, E);
  k_aggr<<<N / 2, 256, 0, stream>>>(offs, esrc, h, as_n, ad_n, bias, out);
}

// Round 4
// 158.769 us; speedup vs baseline: 1.0743x; 1.0743x over previous
//
#include <hip/hip_runtime.h>

#define TPG   4096    // nodes per graph (T)
#define NHEAD 4
#define DIMD  128
#define NEG   0.2f
#define BSZ   8       // aggr edge-batch size

// ---------------------------------------------------------------- edge loads
__device__ __forceinline__ int load_edge(const void* ei, int is64, long idx) {
  if (is64) return (int)((const long long*)ei)[idx];
  return ((const int*)ei)[idx];
}

// Per-block int64/int32 layout vote: 256 threads sample odd dwords 1..511.
__device__ __forceinline__ int detect64_block(const unsigned* __restrict__ ei) {
  __shared__ int s64;
  int t = threadIdx.x;
  if (t == 0) s64 = 1;
  __syncthreads();
  if (t < 256) {
    unsigned v = ei[2 * t + 1];
    if (v != 0u) s64 = 0;     // benign race: all writers write 0
  }
  __syncthreads();
  return s64;
}

// ------------------------------------------------- GEMM h = x*W^T + att dots
// block = 256 threads, 16 nodes/block. Wave w owns head w. Blocks 0..15 also
// zero the hist counters; block 16 zeroes the done counter.
__global__ __launch_bounds__(256) void k_gemm(
    const float* __restrict__ x, const float* __restrict__ W,
    const float* __restrict__ atts, const float* __restrict__ attd,
    float* __restrict__ h, float* __restrict__ as_n, float* __restrict__ ad_n,
    int* __restrict__ counts, int* __restrict__ done) {
  __shared__ float4 xs4[16][33];   // +1 float4 pad
  int t = threadIdx.x;
  if (blockIdx.x < 16) counts[(blockIdx.x << 8) + t] = 0;
  if (blockIdx.x == 16 && t == 0) *done = 0;
  int base = blockIdx.x * 16;
  const float4* x4 = (const float4*)x;
  for (int i = t; i < 512; i += 256) {
    xs4[i >> 5][i & 31] = x4[base * 32 + i];
  }
  __syncthreads();

  int n_sub = t & 15, cgrp = t >> 4;
  int c0 = cgrp * 8;
  const float4* W4 = (const float4*)W;
  float acc[8];
#pragma unroll
  for (int k = 0; k < 8; ++k) acc[k] = 0.f;

  for (int db = 0; db < 32; db += 8) {     // 32 d per chunk
    float4 xa[8];
#pragma unroll
    for (int i = 0; i < 8; ++i) xa[i] = xs4[n_sub][db + i];
#pragma unroll
    for (int k = 0; k < 8; ++k) {
      const float4* wr = W4 + (c0 + k) * 32 + db;
      float a = acc[k];
#pragma unroll
      for (int i = 0; i < 8; ++i) {
        float4 w = wr[i];
        a = fmaf(xa[i].x, w.x, a);
        a = fmaf(xa[i].y, w.y, a);
        a = fmaf(xa[i].z, w.z, a);
        a = fmaf(xa[i].w, w.w, a);
      }
      acc[k] = a;
    }
  }

  int n = base + n_sub;
  float4* hp = (float4*)(h + ((size_t)n << 7) + c0);
  hp[0] = make_float4(acc[0], acc[1], acc[2], acc[3]);
  hp[1] = make_float4(acc[4], acc[5], acc[6], acc[7]);

  float ps = 0.f, pd = 0.f;
#pragma unroll
  for (int k = 0; k < 8; ++k) {
    ps = fmaf(acc[k], atts[c0 + k], ps);
    pd = fmaf(acc[k], attd[c0 + k], pd);
  }
  ps += __shfl_xor(ps, 16); ps += __shfl_xor(ps, 32);
  pd += __shfl_xor(pd, 16); pd += __shfl_xor(pd, 32);
  if ((t & 48) == 0) {
    as_n[(n << 2) + (t >> 6)] = ps;
    ad_n[(n << 2) + (t >> 6)] = pd;
  }
}

// --------------------------------------- CSR: histogram + last-block scan
__global__ __launch_bounds__(256) void k_histscan(
    const void* __restrict__ ei, int* __restrict__ counts,
    int* __restrict__ offs, int* __restrict__ cursor,
    int* __restrict__ done, int E) {
  int is64 = detect64_block((const unsigned*)ei);
  int t = threadIdx.x;
  int e = blockIdx.x * 256 + t;
  if (e < E) {
    int dst = load_edge(ei, is64, (long)E + e);
    atomicAdd(&counts[dst], 1);
  }
  __syncthreads();                       // barrier drains vmcnt: atomics acked
  __shared__ int lastFlag;
  if (t == 0) {
    __threadfence();
    int prev = atomicAdd(done, 1);
    lastFlag = (prev == (int)gridDim.x - 1);
  }
  __syncthreads();
  if (!lastFlag) return;

  int v[16]; int sum = 0;
#pragma unroll
  for (int i = 0; i < 16; ++i) { v[i] = atomicAdd(&counts[t * 16 + i], 0); sum += v[i]; }
  int lane = t & 63, w = t >> 6;
  int sc = sum;
#pragma unroll
  for (int off = 1; off < 64; off <<= 1) {
    int o = __shfl_up(sc, off);
    if (lane >= off) sc += o;
  }
  __shared__ int wsum[4];
  if (lane == 63) wsum[w] = sc;
  __syncthreads();
  int wo = 0;
  for (int i = 0; i < w; ++i) wo += wsum[i];
  int a = wo + sc - sum;
#pragma unroll
  for (int i = 0; i < 16; ++i) {
    offs[t * 16 + i] = a; cursor[t * 16 + i] = a; a += v[i];
  }
  if (t == 255) offs[4096] = a;
}

__global__ __launch_bounds__(256) void k_scatter(const void* __restrict__ ei,
                                                 int* __restrict__ cursor,
                                                 int* __restrict__ esrc, int E) {
  int is64 = detect64_block((const unsigned*)ei);
  int e = blockIdx.x * blockDim.x + threadIdx.x;
  if (e >= E) return;
  int src = load_edge(ei, is64, e);
  int dst = load_edge(ei, is64, (long)E + e);
  int pos = atomicAdd(&cursor[dst], 1);
  esrc[pos] = src;
}

// --------------------------- single-pass flash softmax + aggregation per node
// one wave per node; lane owns channels {2l,2l+1} (float2), head = lane>>4.
// Full batches of 8 edges with UNGUARDED wave-uniform s_loads; software
// pipeline: MATH(t) overlaps VLD(t+1) and IDX(t+2) (A/B register buffers).
#define IDX(sg, t)                                                        \
  { _Pragma("unroll") for (int k = 0; k < BSZ; ++k)                       \
      sg[k] = nodebase + esrc[beg + ((t) << 3) + k]; }

#define VLD(sg, as, hv)                                                   \
  { _Pragma("unroll") for (int k = 0; k < BSZ; ++k)                       \
      as[k] = as_n[(sg[k] << 2) + myh];                                   \
    _Pragma("unroll") for (int k = 0; k < BSZ; ++k)                       \
      hv[k] = h2[((size_t)sg[k] << 6) + lane]; }

#define MATH(as, hv)                                                      \
  { float ek[BSZ];                                                        \
    _Pragma("unroll") for (int k = 0; k < BSZ; ++k) {                     \
      float e = as[k] + adst; ek[k] = e > 0.f ? e : NEG * e; }            \
    float bm = ek[0];                                                     \
    _Pragma("unroll") for (int k = 1; k < BSZ; ++k) bm = fmaxf(bm, ek[k]);\
    float mn = fmaxf(m, bm);                                              \
    float r = __expf(m - mn);                                             \
    float ps = 0.f, px = 0.f, py = 0.f;                                   \
    _Pragma("unroll") for (int k = 0; k < BSZ; ++k) {                     \
      float al = __expf(ek[k] - mn);                                      \
      ps += al;                                                           \
      px = fmaf(al, hv[k].x, px);                                         \
      py = fmaf(al, hv[k].y, py);                                         \
    }                                                                     \
    acc.x = fmaf(acc.x, r, px);                                           \
    acc.y = fmaf(acc.y, r, py);                                           \
    s = fmaf(s, r, ps);                                                   \
    m = mn; }

__global__ __launch_bounds__(256) void k_aggr(
    const int* __restrict__ offs, const int* __restrict__ esrc,
    const float* __restrict__ h, const float* __restrict__ as_n,
    const float* __restrict__ ad_n, const float* __restrict__ bias,
    float* __restrict__ out) {
  int lane = threadIdx.x & 63;
  int n = __builtin_amdgcn_readfirstlane((blockIdx.x << 2) + (threadIdx.x >> 6));
  int tloc = n & (TPG - 1);
  int nodebase = n - tloc;
  int beg = __builtin_amdgcn_readfirstlane(offs[tloc]);
  int end = __builtin_amdgcn_readfirstlane(offs[tloc + 1]);

  int myh = lane >> 4;
  const float2* __restrict__ h2 = (const float2*)h;
  float adst = ad_n[(n << 2) + myh];

  float m, s;
  float2 acc;
  {
    float e = as_n[(n << 2) + myh] + adst;    // self-loop
    e = e > 0.f ? e : NEG * e;
    m = e; s = 1.f;
    acc = h2[((size_t)n << 6) + lane];
  }

  int F = (end - beg) >> 3;       // full batches
  int sgA[BSZ], sgB[BSZ];
  float asA[BSZ], asB[BSZ];
  float2 hvA[BSZ], hvB[BSZ];

  if (F > 0) { IDX(sgA, 0); VLD(sgA, asA, hvA); }
  if (F > 1) { IDX(sgB, 1); }
  int t = 0;
  while (t < F) {
    if (t + 1 < F) VLD(sgB, asB, hvB);
    if (t + 2 < F) IDX(sgA, t + 2);
    MATH(asA, hvA);
    ++t; if (t >= F) break;
    if (t + 1 < F) VLD(sgA, asA, hvA);
    if (t + 2 < F) IDX(sgB, t + 2);
    MATH(asB, hvB);
    ++t;
  }

  // tail (guarded)
  int jt = beg + (F << 3);
  if (jt < end) {
    int sg[BSZ];
#pragma unroll
    for (int k = 0; k < BSZ; ++k) {
      int j = jt + k;
      sg[k] = (j < end) ? (nodebase + esrc[j]) : n;
    }
    float as_[BSZ]; float2 hv[BSZ];
#pragma unroll
    for (int k = 0; k < BSZ; ++k) as_[k] = as_n[(sg[k] << 2) + myh];
#pragma unroll
    for (int k = 0; k < BSZ; ++k) hv[k] = h2[((size_t)sg[k] << 6) + lane];
    float ek[BSZ];
#pragma unroll
    for (int k = 0; k < BSZ; ++k) {
      float e = as_[k] + adst; e = e > 0.f ? e : NEG * e;
      ek[k] = (jt + k < end) ? e : -1e30f;
    }
    float bm = ek[0];
#pragma unroll
    for (int k = 1; k < BSZ; ++k) bm = fmaxf(bm, ek[k]);
    float mn = fmaxf(m, bm);
    float r = __expf(m - mn);
    float ps = 0.f, px = 0.f, py = 0.f;
#pragma unroll
    for (int k = 0; k < BSZ; ++k) {
      float al = __expf(ek[k] - mn);
      ps += al;
      px = fmaf(al, hv[k].x, px);
      py = fmaf(al, hv[k].y, py);
    }
    acc.x = fmaf(acc.x, r, px);
    acc.y = fmaf(acc.y, r, py);
    s = fmaf(s, r, ps);
    m = mn;
  }

  float invs = 1.f / (s + 1e-16f);
  int c = lane << 1;
  const float2 bi = *(const float2*)(bias + c);
  float2 o;
  o.x = fmaf(acc.x, invs, bi.x);
  o.y = fmaf(acc.y, invs, bi.y);
  *(float2*)(out + ((size_t)n << 7) + c) = o;
}

// ---------------------------------------------------------------------- host
extern "C" void kernel_launch(void* const* d_in, const int* in_sizes, int n_in,
                              void* d_out, int out_size, void* d_ws, size_t ws_size,
                              hipStream_t stream) {
  const float* x    = (const float*)d_in[0];
  const void*  ei   = d_in[1];
  const float* W    = (const float*)d_in[2];
  const float* atts = (const float*)d_in[3];
  const float* attd = (const float*)d_in[4];
  const float* bias = (const float*)d_in[5];
  float* out = (float*)d_out;

  int N = in_sizes[0] / DIMD;   // 16384
  int E = in_sizes[1] / 2;      // 131072

  char* p = (char*)d_ws;
  float* h      = (float*)p; p += (size_t)N * DIMD * 4;
  float* as_n   = (float*)p; p += (size_t)N * NHEAD * 4;
  float* ad_n   = (float*)p; p += (size_t)N * NHEAD * 4;
  int*   counts = (int*)p;   p += (size_t)TPG * 4;
  int*   offs   = (int*)p;   p += (size_t)(TPG + 1) * 4;
  int*   cursor = (int*)p;   p += (size_t)TPG * 4;
  int*   esrc   = (int*)p;   p += (size_t)E * 4;
  int*   done   = (int*)p;   p += 4;

  k_gemm<<<N / 16, 256, 0, stream>>>(x, W, atts, attd, h, as_n, ad_n, counts, done);
  k_histscan<<<(E + 255) / 256, 256, 0, stream>>>(ei, counts, offs, cursor, done, E);
  k_scatter<<<(E + 255) / 256, 256, 0, stream>>>(ei, cursor, esrc, E);
  k_aggr<<<N / 4, 256, 0, stream>>>(offs, esrc, h, as_n, ad_n, bias, out);
}